// Round 1
// baseline (457.413 us; speedup 1.0000x reference)
//
#include <hip/hip_runtime.h>
#include <hip/hip_bf16.h>

// Problem constants (from setup_inputs): B=8, d=16, H=W=512, K=8
#define BB 8
#define DD 16
#define KK 8
#define NN (512 * 512)

constexpr int BPB = 64;   // blocks per batch  -> grid = 8*64 = 512
constexpr int T   = 256;  // threads per block

// ws layout (floats):
//   [0, 1024)      sums      [B][K][D]   (atomic targets, zeroed)
//   [1024, 1088)   counts    [B][K]      (atomic targets, zeroed)
//   [1088, 2112)   centers   [B][K][D]
//   [2112, 2120)   distreg   [B]         (dist_term + reg_term per batch)
//   [2120, 2184)   var_sums  [B][K]      (atomic targets, zeroed)
#define WS_SUMS    0
#define WS_CNTS    1024
#define WS_CENTERS 1088
#define WS_DISTREG 2112
#define WS_VARSUMS 2120
#define WS_TOTAL   2184

__device__ __forceinline__ float fcomp(const float4& v, int p) {
    switch (p) { case 0: return v.x; case 1: return v.y; case 2: return v.z; default: return v.w; }
}

__device__ __forceinline__ float wred64(float x) {
#pragma unroll
    for (int m = 1; m < 64; m <<= 1) x += __shfl_xor(x, m, 64);
    return x;
}

// ---------------- Pass 1: per-(b,k) sums and counts -------------------------
__global__ __launch_bounds__(T, 2) void k_sums(const float* __restrict__ data,
                                               const int* __restrict__ labels,
                                               float* __restrict__ ws) {
    const int b   = blockIdx.x / BPB;
    const int blk = blockIdx.x % BPB;
    const float4* dp4 = (const float4*)(data + (size_t)b * DD * NN);
    const int4*   lp4 = (const int4*)(labels + (size_t)b * NN);

    float s[KK][DD];
    float c[KK];
#pragma unroll
    for (int k = 0; k < KK; ++k) {
        c[k] = 0.f;
#pragma unroll
        for (int d = 0; d < DD; ++d) s[k][d] = 0.f;
    }

    const int G = NN / 4;  // 65536 float4-groups per batch
    for (int g = blk * T + threadIdx.x; g < G; g += BPB * T) {
        int4 lab = lp4[g];
        int labs[4] = {lab.x, lab.y, lab.z, lab.w};
        float ind[4][KK];
#pragma unroll
        for (int p = 0; p < 4; ++p) {
#pragma unroll
            for (int k = 0; k < KK; ++k) {
                float iv = (labs[p] == k) ? 1.0f : 0.0f;
                ind[p][k] = iv;
                c[k] += iv;
            }
        }
#pragma unroll
        for (int d = 0; d < DD; ++d) {
            float4 x = dp4[(size_t)d * (NN / 4) + g];
#pragma unroll
            for (int p = 0; p < 4; ++p) {
                float xv = fcomp(x, p);
#pragma unroll
                for (int k = 0; k < KK; ++k) s[k][d] = fmaf(ind[p][k], xv, s[k][d]);
            }
        }
    }

    float* sums = ws + WS_SUMS;
    float* cnts = ws + WS_CNTS;
    const int lane = threadIdx.x & 63;
#pragma unroll
    for (int k = 0; k < KK; ++k) {
        float cc = wred64(c[k]);
        if (lane == 0) atomicAdd(&cnts[b * KK + k], cc);
#pragma unroll
        for (int d = 0; d < DD; ++d) {
            float sv = wred64(s[k][d]);
            if (lane == 0) atomicAdd(&sums[(b * KK + k) * DD + d], sv);
        }
    }
}

// ---------------- Centers + dist/reg terms (tiny) ---------------------------
__global__ void k_centers(float* __restrict__ ws) {
    const int t = threadIdx.x;  // 0..63 : b = t>>3, k = t&7
    const int b = t >> 3, k = t & 7;
    const float cnt = ws[WS_CNTS + t];
    const float inv = 1.0f / cnt;
    __shared__ float sc[BB * KK][DD];
    float cen[DD];
    float n2 = 0.f;
#pragma unroll
    for (int d = 0; d < DD; ++d) {
        float v = ws[WS_SUMS + t * DD + d] * inv;
        cen[d] = v;
        sc[t][d] = v;
        ws[WS_CENTERS + t * DD + d] = v;
        n2 = fmaf(v, v, n2);
    }
    __syncthreads();
    // reg term: clip(||c|| - sqrt(16), 0)^2
    float rg = fmaxf(sqrtf(n2) - 4.0f, 0.f);
    rg *= rg;
    // pairwise distance term (diagonal neutralized by +DELTA_DIST, like eye trick)
    float rowcost = 0.f;
#pragma unroll
    for (int j = 0; j < KK; ++j) {
        float d2 = 0.f;
#pragma unroll
        for (int d = 0; d < DD; ++d) {
            float df = cen[d] - sc[b * KK + j][d];
            d2 = fmaf(df, df, d2);
        }
        float dm = sqrtf(d2) + ((j == k) ? 2.0f : 0.0f);
        float h = fmaxf(2.0f - dm, 0.f);
        rowcost += h * h;
    }
#pragma unroll
    for (int m = 1; m < 8; m <<= 1) {
        rowcost += __shfl_xor(rowcost, m, 64);
        rg += __shfl_xor(rg, m, 64);
    }
    if (k == 0)
        ws[WS_DISTREG + b] = rowcost / (float)(KK * (KK - 1)) + rg / (float)KK;
}

// ---------------- Pass 2: variance term -------------------------------------
__global__ __launch_bounds__(T) void k_var(const float* __restrict__ data,
                                           const int* __restrict__ labels,
                                           float* __restrict__ ws) {
    const int b   = blockIdx.x / BPB;
    const int blk = blockIdx.x % BPB;
    __shared__ float4 cs[KK * 4];  // centers of this batch: [K][4 float4]
    if (threadIdx.x < KK * 4)
        cs[threadIdx.x] = ((const float4*)(ws + WS_CENTERS + b * KK * DD))[threadIdx.x];
    __syncthreads();

    const float4* dp4 = (const float4*)(data + (size_t)b * DD * NN);
    const int4*   lp4 = (const int4*)(labels + (size_t)b * NN);

    float acc[KK];
#pragma unroll
    for (int k = 0; k < KK; ++k) acc[k] = 0.f;

    const int G = NN / 4;
    for (int g = blk * T + threadIdx.x; g < G; g += BPB * T) {
        int4 lab = lp4[g];
        float4 x[DD];
#pragma unroll
        for (int d = 0; d < DD; ++d) x[d] = dp4[(size_t)d * (NN / 4) + g];
        int labs[4] = {lab.x, lab.y, lab.z, lab.w};
#pragma unroll
        for (int p = 0; p < 4; ++p) {
            const int l = labs[p];
            float ss = 0.f;
#pragma unroll
            for (int q = 0; q < 4; ++q) {
                float4 cv = cs[l * 4 + q];
                float d0 = fcomp(x[q * 4 + 0], p) - cv.x; ss = fmaf(d0, d0, ss);
                float d1 = fcomp(x[q * 4 + 1], p) - cv.y; ss = fmaf(d1, d1, ss);
                float d2 = fcomp(x[q * 4 + 2], p) - cv.z; ss = fmaf(d2, d2, ss);
                float d3 = fcomp(x[q * 4 + 3], p) - cv.w; ss = fmaf(d3, d3, ss);
            }
            float e = fmaxf(sqrtf(ss) - 1.0f, 0.f);  // DELTA_VAR = 1
            float e2 = e * e;
#pragma unroll
            for (int k = 0; k < KK; ++k) acc[k] += (l == k) ? e2 : 0.f;
        }
    }

    float* var_sums = ws + WS_VARSUMS;
    const int lane = threadIdx.x & 63;
#pragma unroll
    for (int k = 0; k < KK; ++k) {
        float a = wred64(acc[k]);
        if (lane == 0) atomicAdd(&var_sums[b * KK + k], a);
    }
}

// ---------------- Final combine ---------------------------------------------
__global__ void k_final(const float* __restrict__ ws, float* __restrict__ out) {
    const int t = threadIdx.x;  // 0..63
    const int b = t >> 3;
    float v = ws[WS_VARSUMS + t] / ws[WS_CNTS + t];
#pragma unroll
    for (int m = 1; m < 8; m <<= 1) v += __shfl_xor(v, m, 64);  // sum over k
    float term = v / (float)KK + ws[WS_DISTREG + b];
#pragma unroll
    for (int m = 8; m < 64; m <<= 1) term += __shfl_xor(term, m, 64);  // sum over b
    if (t == 0) out[0] = term / (float)BB;
}

extern "C" void kernel_launch(void* const* d_in, const int* in_sizes, int n_in,
                              void* d_out, int out_size, void* d_ws, size_t ws_size,
                              hipStream_t stream) {
    const float* data   = (const float*)d_in[0];
    const int*   labels = (const int*)d_in[1];
    float*       ws     = (float*)d_ws;

    hipMemsetAsync(d_ws, 0, WS_TOTAL * sizeof(float), stream);
    k_sums<<<BB * BPB, T, 0, stream>>>(data, labels, ws);
    k_centers<<<1, 64, 0, stream>>>(ws);
    k_var<<<BB * BPB, T, 0, stream>>>(data, labels, ws);
    k_final<<<1, 64, 0, stream>>>(ws, (float*)d_out);
}

// Round 2
// 260.605 us; speedup vs baseline: 1.7552x; 1.7552x over previous
//
#include <hip/hip_runtime.h>
#include <hip/hip_bf16.h>

// Problem constants: B=8, d=16, H=W=512, K=8
#define BB 8
#define DD 16
#define KK 8
#define NN (512 * 512)
#define G4 (NN / 4)               // 65536 float4-groups per batch

constexpr int BPB   = 256;        // blocks per batch -> grid = 2048
constexpr int T     = 256;        // threads per block (4 waves)
constexpr int WV    = T / 64;     // waves per block = 4
constexpr int WPB   = BPB * WV;   // waves per batch = 1024
constexpr int SLOTS = WPB * 4;    // float4-groups consumed per sweep = 4096
constexpr int ITERS = G4 / SLOTS; // 16

// ws layout (floats):
#define WS_SUMS    0      // [B][K][D]  (atomics, zeroed)
#define WS_CNTS    1024   // [B][K]     (atomics, zeroed)
#define WS_CENTERS 1088   // [B][K][D]
#define WS_DISTREG 2112   // [B]
#define WS_VARSUMS 2120   // [B][K]     (atomics, zeroed)
#define WS_TOTAL   2184

__device__ __forceinline__ float fcomp(const float4& v, int p) {
    switch (p) { case 0: return v.x; case 1: return v.y; case 2: return v.z; default: return v.w; }
}

// ---------------- Pass 1: per-(b,k) sums and counts -------------------------
// Lane split: d = lane>>2 (owned dim), r = lane&3 (point sub-group).
// Per-thread accumulators: s[K] (one dim) + c[K]  -> ~35 VGPRs, no spill.
__global__ __launch_bounds__(T, 8) void k_sums(const float* __restrict__ data,
                                               const int* __restrict__ labels,
                                               float* __restrict__ ws) {
    const int b    = blockIdx.x / BPB;
    const int blk  = blockIdx.x % BPB;
    const int tid  = threadIdx.x;
    const int wv   = tid >> 6;
    const int lane = tid & 63;
    const int d    = lane >> 2;
    const int r    = lane & 3;
    const int w    = blk * WV + wv;   // wave id within batch [0, WPB)

    const float4* dp4 = (const float4*)(data + (size_t)b * DD * NN) + (size_t)d * G4;
    const int4*   lp4 = (const int4*)(labels + (size_t)b * NN);

    float s[KK], c[KK];
#pragma unroll
    for (int k = 0; k < KK; ++k) { s[k] = 0.f; c[k] = 0.f; }

#pragma unroll 4
    for (int i = 0; i < ITERS; ++i) {
        const int gg = i * SLOTS + w * 4 + r;
        float4 x  = dp4[gg];
        int4   lb = lp4[gg];
        int labs[4] = {lb.x, lb.y, lb.z, lb.w};
#pragma unroll
        for (int p = 0; p < 4; ++p) {
            float xv = fcomp(x, p);
            int   l  = labs[p];
#pragma unroll
            for (int k = 0; k < KK; ++k) {
                bool m = (l == k);
                s[k] += m ? xv : 0.0f;
                c[k] += m ? 1.0f : 0.0f;
            }
        }
    }

    // reduce over r (same d, 4 lanes)
#pragma unroll
    for (int k = 0; k < KK; ++k) {
        s[k] += __shfl_xor(s[k], 1, 64);
        s[k] += __shfl_xor(s[k], 2, 64);
        c[k] += __shfl_xor(c[k], 1, 64);
        c[k] += __shfl_xor(c[k], 2, 64);
    }

    __shared__ float sred[WV][DD][KK];
    __shared__ float cred[WV][KK];
    if (r == 0) {
#pragma unroll
        for (int k = 0; k < KK; ++k) sred[wv][d][k] = s[k];
        if (d == 0) {
#pragma unroll
            for (int k = 0; k < KK; ++k) cred[wv][k] = c[k];
        }
    }
    __syncthreads();

    if (tid < DD * KK) {                       // 128 threads: one (d,k) each
        const int dd = tid >> 3, k = tid & 7;
        float v = 0.f;
#pragma unroll
        for (int ww = 0; ww < WV; ++ww) v += sred[ww][dd][k];
        atomicAdd(&ws[WS_SUMS + (b * KK + k) * DD + dd], v);
    }
    if (tid >= 128 && tid < 128 + KK) {        // 8 threads: counts
        const int k = tid - 128;
        float v = 0.f;
#pragma unroll
        for (int ww = 0; ww < WV; ++ww) v += cred[ww][k];
        atomicAdd(&ws[WS_CNTS + b * KK + k], v);
    }
}

// ---------------- Centers + dist/reg terms (tiny) ---------------------------
__global__ void k_centers(float* __restrict__ ws) {
    const int t = threadIdx.x;  // 0..63 : b = t>>3, k = t&7
    const int b = t >> 3, k = t & 7;
    const float inv = 1.0f / ws[WS_CNTS + t];
    __shared__ float sc[BB * KK][DD];
    float cen[DD];
    float n2 = 0.f;
#pragma unroll
    for (int d = 0; d < DD; ++d) {
        float v = ws[WS_SUMS + t * DD + d] * inv;
        cen[d] = v;
        sc[t][d] = v;
        ws[WS_CENTERS + t * DD + d] = v;
        n2 = fmaf(v, v, n2);
    }
    __syncthreads();
    float rg = fmaxf(sqrtf(n2) - 4.0f, 0.f);   // delta_reg = sqrt(16) = 4
    rg *= rg;
    float rowcost = 0.f;
#pragma unroll
    for (int j = 0; j < KK; ++j) {
        float d2 = 0.f;
#pragma unroll
        for (int d = 0; d < DD; ++d) {
            float df = cen[d] - sc[b * KK + j][d];
            d2 = fmaf(df, df, d2);
        }
        float dm = sqrtf(d2) + ((j == k) ? 2.0f : 0.0f);  // eye*DELTA_DIST trick
        float h = fmaxf(2.0f - dm, 0.f);
        rowcost += h * h;
    }
#pragma unroll
    for (int m = 1; m < 8; m <<= 1) {
        rowcost += __shfl_xor(rowcost, m, 64);
        rg      += __shfl_xor(rg, m, 64);
    }
    if (k == 0)
        ws[WS_DISTREG + b] = rowcost / (float)(KK * (KK - 1)) + rg / (float)KK;
}

// ---------------- Pass 2: variance term -------------------------------------
__global__ __launch_bounds__(T, 8) void k_var(const float* __restrict__ data,
                                              const int* __restrict__ labels,
                                              float* __restrict__ ws) {
    const int b    = blockIdx.x / BPB;
    const int blk  = blockIdx.x % BPB;
    const int tid  = threadIdx.x;
    const int wv   = tid >> 6;
    const int lane = tid & 63;
    const int d    = lane >> 2;
    const int r    = lane & 3;
    const int w    = blk * WV + wv;

    __shared__ float cs[KK * DD];              // centers [k][d] of this batch
    if (tid < KK * DD) cs[tid] = ws[WS_CENTERS + b * KK * DD + tid];
    __syncthreads();

    const float4* dp4 = (const float4*)(data + (size_t)b * DD * NN) + (size_t)d * G4;
    const int4*   lp4 = (const int4*)(labels + (size_t)b * NN);

    float acc[KK];
#pragma unroll
    for (int k = 0; k < KK; ++k) acc[k] = 0.f;

#pragma unroll 4
    for (int i = 0; i < ITERS; ++i) {
        const int gg = i * SLOTS + w * 4 + r;
        float4 x  = dp4[gg];
        int4   lb = lp4[gg];
        int labs[4] = {lb.x, lb.y, lb.z, lb.w};
#pragma unroll
        for (int p = 0; p < 4; ++p) {
            const int l = labs[p];
            float cv = cs[l * DD + d];
            float pd = fcomp(x, p) - cv;
            float ss = pd * pd;
            // reduce over d (lanes differing in bits 2..5)
            ss += __shfl_xor(ss, 4, 64);
            ss += __shfl_xor(ss, 8, 64);
            ss += __shfl_xor(ss, 16, 64);
            ss += __shfl_xor(ss, 32, 64);
            float e = fmaxf(sqrtf(ss) - 1.0f, 0.f);   // DELTA_VAR = 1
            float e2 = e * e;
#pragma unroll
            for (int k = 0; k < KK; ++k) acc[k] += (l == k) ? e2 : 0.0f;
        }
    }

    // acc identical across d-groups; reduce over r, take lane 0
#pragma unroll
    for (int k = 0; k < KK; ++k) {
        acc[k] += __shfl_xor(acc[k], 1, 64);
        acc[k] += __shfl_xor(acc[k], 2, 64);
    }
    __shared__ float vred[WV][KK];
    if (lane == 0) {
#pragma unroll
        for (int k = 0; k < KK; ++k) vred[wv][k] = acc[k];
    }
    __syncthreads();
    if (tid < KK) {
        float v = 0.f;
#pragma unroll
        for (int ww = 0; ww < WV; ++ww) v += vred[ww][tid];
        atomicAdd(&ws[WS_VARSUMS + b * KK + tid], v);
    }
}

// ---------------- Final combine ---------------------------------------------
__global__ void k_final(const float* __restrict__ ws, float* __restrict__ out) {
    const int t = threadIdx.x;  // 0..63
    const int b = t >> 3;
    float v = ws[WS_VARSUMS + t] / ws[WS_CNTS + t];
#pragma unroll
    for (int m = 1; m < 8; m <<= 1) v += __shfl_xor(v, m, 64);   // sum over k
    float term = v / (float)KK + ws[WS_DISTREG + b];
#pragma unroll
    for (int m = 8; m < 64; m <<= 1) term += __shfl_xor(term, m, 64);  // sum over b
    if (t == 0) out[0] = term / (float)BB;
}

extern "C" void kernel_launch(void* const* d_in, const int* in_sizes, int n_in,
                              void* d_out, int out_size, void* d_ws, size_t ws_size,
                              hipStream_t stream) {
    const float* data   = (const float*)d_in[0];
    const int*   labels = (const int*)d_in[1];
    float*       ws     = (float*)d_ws;

    hipMemsetAsync(d_ws, 0, WS_TOTAL * sizeof(float), stream);
    k_sums<<<BB * BPB, T, 0, stream>>>(data, labels, ws);
    k_centers<<<1, 64, 0, stream>>>(ws);
    k_var<<<BB * BPB, T, 0, stream>>>(data, labels, ws);
    k_final<<<1, 64, 0, stream>>>(ws, (float*)d_out);
}

// Round 3
// 237.160 us; speedup vs baseline: 1.9287x; 1.0989x over previous
//
#include <hip/hip_runtime.h>
#include <hip/hip_bf16.h>

// Problem constants: B=8, d=16, H=W=512, K=8
#define BB 8
#define DD 16
#define KK 8
#define NN (512 * 512)
#define G4 (NN / 4)               // 65536 float4-groups per batch

constexpr int BPB = 256;          // blocks per batch -> grid = 2048
constexpr int T   = 256;          // threads per block (4 waves)
constexpr int WV  = 4;            // waves per block
constexpr int WPB = BPB * WV;     // waves per batch = 1024
constexpr int SL  = WPB * 8;      // float4-groups per sweep (pass 1) = 8192
constexpr int IT1 = G4 / SL;      // 8 iterations per thread (pass 1)

// ws layout (floats):
#define WS_SUMS    0      // [B][K][D]  (atomics, zeroed)
#define WS_CNTS    1024   // [B][K]     (atomics, zeroed)
#define WS_VARSUMS 1088   // [B][K]     (atomics, zeroed)
#define WS_TOTAL   1152

// ---------------- Pass 1: per-(b,k) sums and counts -------------------------
// Lane map: d8 = lane>>3 (owns dims d8 and d8+8), r8 = lane&7 (point group).
// Wave reads 8 dims x 128 B contiguous segments per instruction pair.
// Counts via ballot/popcount on the scalar pipe (8 lanes per point -> /8).
__global__ __launch_bounds__(T, 8) void k_sums(const float* __restrict__ data,
                                               const int* __restrict__ labels,
                                               float* __restrict__ ws) {
    const int b    = blockIdx.x / BPB;
    const int blk  = blockIdx.x % BPB;
    const int tid  = threadIdx.x;
    const int wv   = tid >> 6;
    const int lane = tid & 63;
    const int d8   = lane >> 3;
    const int r8   = lane & 7;
    const int w    = blk * WV + wv;          // wave id within batch

    const float4* dlo = (const float4*)(data + (size_t)b * DD * NN) + (size_t)d8 * G4;
    const float4* dhi = dlo + (size_t)8 * G4;
    const int4*   lp4 = (const int4*)(labels + (size_t)b * NN);

    float slo[KK], shi[KK];
    unsigned int cnt[KK];
#pragma unroll
    for (int k = 0; k < KK; ++k) { slo[k] = 0.f; shi[k] = 0.f; cnt[k] = 0u; }

#pragma unroll 2
    for (int i = 0; i < IT1; ++i) {
        const int gg = i * SL + w * 8 + r8;
        float4 xlo = dlo[gg];
        float4 xhi = dhi[gg];
        int4   lb  = lp4[gg];
        int   labs[4] = {lb.x, lb.y, lb.z, lb.w};
        float xl[4]   = {xlo.x, xlo.y, xlo.z, xlo.w};
        float xh[4]   = {xhi.x, xhi.y, xhi.z, xhi.w};
#pragma unroll
        for (int p = 0; p < 4; ++p) {
            const int   l = labs[p];
            const float a = xl[p];
            const float h = xh[p];
#pragma unroll
            for (int k = 0; k < KK; ++k) {
                bool m = (l == k);
                slo[k] += m ? a : 0.f;
                shi[k] += m ? h : 0.f;
                cnt[k] += (unsigned)__popcll(__ballot(m));   // scalar-pipe count
            }
        }
    }

    // reduce over r8 (lane bits 0..2)
#pragma unroll
    for (int k = 0; k < KK; ++k) {
#pragma unroll
        for (int m = 1; m < 8; m <<= 1) {
            slo[k] += __shfl_xor(slo[k], m, 64);
            shi[k] += __shfl_xor(shi[k], m, 64);
        }
    }

    __shared__ float sred[WV][DD][KK];
    __shared__ float cred[WV][KK];
    if (r8 == 0) {
#pragma unroll
        for (int k = 0; k < KK; ++k) {
            sred[wv][d8][k]     = slo[k];
            sred[wv][d8 + 8][k] = shi[k];
        }
    }
    if (lane == 0) {
#pragma unroll
        for (int k = 0; k < KK; ++k) cred[wv][k] = (float)(cnt[k] >> 3);  // /8 lanes per point
    }
    __syncthreads();

    if (tid < DD * KK) {                 // 128 threads: one (d,k) each
        const int dd = tid >> 3, k = tid & 7;
        float v = 0.f;
#pragma unroll
        for (int q = 0; q < WV; ++q) v += sred[q][dd][k];
        atomicAdd(&ws[WS_SUMS + (b * KK + k) * DD + dd], v);
    } else if (tid < DD * KK + KK) {     // 8 threads: counts
        const int k = tid - DD * KK;
        float v = 0.f;
#pragma unroll
        for (int q = 0; q < WV; ++q) v += cred[q][k];
        atomicAdd(&ws[WS_CNTS + b * KK + k], v);
    }
}

// ---------------- Pass 2: variance term (lane-owns-point, no shuffles) ------
__global__ __launch_bounds__(T, 8) void k_var(const float* __restrict__ data,
                                              const int* __restrict__ labels,
                                              float* __restrict__ ws) {
    const int b   = blockIdx.x / BPB;
    const int blk = blockIdx.x % BPB;
    const int tid = threadIdx.x;

    __shared__ float cs[KK * 17 + DD];   // centers, stride-17 padded (conflict-free)
    if (tid < KK * DD) {
        const int k = tid >> 4, d = tid & 15;
        cs[k * 17 + d] = ws[WS_SUMS + (b * KK + k) * DD + d] / ws[WS_CNTS + b * KK + k];
    }
    __syncthreads();

    const float4* dp4 = (const float4*)(data + (size_t)b * DD * NN);
    const int4*   lp4 = (const int4*)(labels + (size_t)b * NN);
    const int g = blk * T + tid;         // one float4-group (4 points) per thread

    int4 lb = lp4[g];
    int labs[4] = {lb.x, lb.y, lb.z, lb.w};
    float ss[4] = {0.f, 0.f, 0.f, 0.f};
#pragma unroll 4
    for (int d = 0; d < DD; ++d) {
        float4 x = dp4[(size_t)d * G4 + g];      // 1 KB contiguous per wave
        float xs[4] = {x.x, x.y, x.z, x.w};
#pragma unroll
        for (int p = 0; p < 4; ++p) {
            float c  = cs[labs[p] * 17 + d];     // broadcast / distinct banks
            float df = xs[p] - c;
            ss[p] = fmaf(df, df, ss[p]);
        }
    }

    float acc[KK];
#pragma unroll
    for (int k = 0; k < KK; ++k) acc[k] = 0.f;
#pragma unroll
    for (int p = 0; p < 4; ++p) {
        float e  = fmaxf(sqrtf(ss[p]) - 1.0f, 0.f);   // DELTA_VAR = 1
        float e2 = e * e;
#pragma unroll
        for (int k = 0; k < KK; ++k) acc[k] += (labs[p] == k) ? e2 : 0.f;
    }

    const int lane = tid & 63, wv = tid >> 6;
#pragma unroll
    for (int k = 0; k < KK; ++k) {
#pragma unroll
        for (int m = 1; m < 64; m <<= 1) acc[k] += __shfl_xor(acc[k], m, 64);
    }
    __shared__ float vred[WV][KK];
    if (lane == 0) {
#pragma unroll
        for (int k = 0; k < KK; ++k) vred[wv][k] = acc[k];
    }
    __syncthreads();
    if (tid < KK) {
        float v = 0.f;
#pragma unroll
        for (int q = 0; q < WV; ++q) v += vred[q][tid];
        atomicAdd(&ws[WS_VARSUMS + b * KK + tid], v);
    }
}

// ---------------- Final: centers + dist/reg/var combine ---------------------
__global__ void k_final(const float* __restrict__ ws, float* __restrict__ out) {
    const int t = threadIdx.x;           // 0..63 : b = t>>3, k = t&7
    const int b = t >> 3, k = t & 7;
    const float inv = 1.0f / ws[WS_CNTS + t];
    __shared__ float sc[BB * KK][DD];
    float cen[DD];
    float n2 = 0.f;
#pragma unroll
    for (int d = 0; d < DD; ++d) {
        float v = ws[WS_SUMS + t * DD + d] * inv;
        cen[d] = v;
        sc[t][d] = v;
        n2 = fmaf(v, v, n2);
    }
    __syncthreads();
    float rg = fmaxf(sqrtf(n2) - 4.0f, 0.f);   // delta_reg = sqrt(16) = 4
    rg *= rg;
    float rowcost = 0.f;
#pragma unroll
    for (int j = 0; j < KK; ++j) {
        float d2 = 0.f;
#pragma unroll
        for (int d = 0; d < DD; ++d) {
            float df = cen[d] - sc[b * KK + j][d];
            d2 = fmaf(df, df, d2);
        }
        float dm = sqrtf(d2) + ((j == k) ? 2.0f : 0.0f);   // eye*DELTA_DIST trick
        float h = fmaxf(2.0f - dm, 0.f);
        rowcost += h * h;
    }
    float var  = ws[WS_VARSUMS + t] * inv;
    float term = var / (float)KK + rowcost / 56.0f + rg / (float)KK;
#pragma unroll
    for (int m = 1; m < 64; m <<= 1) term += __shfl_xor(term, m, 64);
    if (t == 0) out[0] = term / (float)BB;
}

extern "C" void kernel_launch(void* const* d_in, const int* in_sizes, int n_in,
                              void* d_out, int out_size, void* d_ws, size_t ws_size,
                              hipStream_t stream) {
    const float* data   = (const float*)d_in[0];
    const int*   labels = (const int*)d_in[1];
    float*       ws     = (float*)d_ws;

    hipMemsetAsync(d_ws, 0, WS_TOTAL * sizeof(float), stream);
    k_sums<<<BB * BPB, T, 0, stream>>>(data, labels, ws);
    k_var<<<BB * BPB, T, 0, stream>>>(data, labels, ws);
    k_final<<<1, 64, 0, stream>>>(ws, (float*)d_out);
}

// Round 6
// 236.110 us; speedup vs baseline: 1.9373x; 1.0044x over previous
//
#include <hip/hip_runtime.h>
#include <hip/hip_bf16.h>

// Problem constants: B=8, d=16, H=W=512, K=8
#define BB 8
#define DD 16
#define KK 8
#define NN (512 * 512)
#define G4 (NN / 4)               // 65536 float4-groups per batch

constexpr int BPB = 256;          // blocks per batch -> grid = 2048
constexpr int T   = 256;          // threads per block (4 waves)
constexpr int WV  = 4;            // waves per block
constexpr int WPB = BPB * WV;     // waves per batch = 1024
constexpr int SL  = WPB * 8;      // float4-groups per sweep (pass 1) = 8192
constexpr int IT1 = G4 / SL;      // 8 iterations per thread (pass 1)

// ws layout (floats):
#define WS_SUMS    0      // [B][K][D]  (atomics, zeroed)
#define WS_CNTS    1024   // [B][K]     (atomics, zeroed)
#define WS_VARSUMS 1088   // [B][K]     (atomics, zeroed)
#define WS_TOTAL   1152

// ---------------- Pass 1: per-(b,k) sums and counts -------------------------
// Lane map: d8 = lane>>3 (owns dims d8 and d8+8), r8 = lane&7 (point group).
// Wave reads 8 dims x 128 B contiguous segments per instruction pair.
// Counts via ballot/popcount on the scalar pipe (8 lanes see each point -> /8).
// launch_bounds(256,4): 128-VGPR cap -> no spill; unroll 4 -> 12 loads in
// flight per thread for latency hiding at 4 waves/SIMD.
__global__ __launch_bounds__(T, 4) void k_sums(const float* __restrict__ data,
                                               const int* __restrict__ labels,
                                               float* __restrict__ ws) {
    const int b    = blockIdx.x / BPB;
    const int blk  = blockIdx.x % BPB;
    const int tid  = threadIdx.x;
    const int wv   = tid >> 6;
    const int lane = tid & 63;
    const int d8   = lane >> 3;
    const int r8   = lane & 7;
    const int w    = blk * WV + wv;          // wave id within batch

    const float4* dlo = (const float4*)(data + (size_t)b * DD * NN) + (size_t)d8 * G4;
    const float4* dhi = dlo + (size_t)8 * G4;
    const int4*   lp4 = (const int4*)(labels + (size_t)b * NN);

    float slo[KK], shi[KK];
    unsigned int cnt[KK];
#pragma unroll
    for (int k = 0; k < KK; ++k) { slo[k] = 0.f; shi[k] = 0.f; cnt[k] = 0u; }

#pragma unroll 4
    for (int i = 0; i < IT1; ++i) {
        const int gg = i * SL + w * 8 + r8;
        float4 xlo = dlo[gg];
        float4 xhi = dhi[gg];
        int4   lb  = lp4[gg];
        int   labs[4] = {lb.x, lb.y, lb.z, lb.w};
        float xl[4]   = {xlo.x, xlo.y, xlo.z, xlo.w};
        float xh[4]   = {xhi.x, xhi.y, xhi.z, xhi.w};
#pragma unroll
        for (int p = 0; p < 4; ++p) {
            const int   l = labs[p];
            const float a = xl[p];
            const float h = xh[p];
#pragma unroll
            for (int k = 0; k < KK; ++k) {
                bool m = (l == k);
                slo[k] += m ? a : 0.f;
                shi[k] += m ? h : 0.f;
                cnt[k] += (unsigned)__popcll(__ballot(m));   // uniform -> SALU
            }
        }
    }

    // reduce over r8 (lane bits 0..2)
#pragma unroll
    for (int k = 0; k < KK; ++k) {
#pragma unroll
        for (int m = 1; m < 8; m <<= 1) {
            slo[k] += __shfl_xor(slo[k], m, 64);
            shi[k] += __shfl_xor(shi[k], m, 64);
        }
    }

    __shared__ float sred[WV][DD][KK];
    __shared__ float cred[WV][KK];
    if (r8 == 0) {
#pragma unroll
        for (int k = 0; k < KK; ++k) {
            sred[wv][d8][k]     = slo[k];
            sred[wv][d8 + 8][k] = shi[k];
        }
    }
    if (lane == 0) {
#pragma unroll
        for (int k = 0; k < KK; ++k) cred[wv][k] = (float)(cnt[k] >> 3);  // /8 lanes per point
    }
    __syncthreads();

    if (tid < DD * KK) {                 // 128 threads: one (d,k) each
        const int dd = tid >> 3, k = tid & 7;
        float v = 0.f;
#pragma unroll
        for (int q = 0; q < WV; ++q) v += sred[q][dd][k];
        atomicAdd(&ws[WS_SUMS + (b * KK + k) * DD + dd], v);
    } else if (tid < DD * KK + KK) {     // 8 threads: counts
        const int k = tid - DD * KK;
        float v = 0.f;
#pragma unroll
        for (int q = 0; q < WV; ++q) v += cred[q][k];
        atomicAdd(&ws[WS_CNTS + b * KK + k], v);
    }
}

// ---------------- Pass 2: variance term (lane-owns-point, no shuffles) ------
__global__ __launch_bounds__(T, 8) void k_var(const float* __restrict__ data,
                                              const int* __restrict__ labels,
                                              float* __restrict__ ws) {
    const int b   = blockIdx.x / BPB;
    const int blk = blockIdx.x % BPB;
    const int tid = threadIdx.x;

    __shared__ float cs[KK * 17 + DD];   // centers, stride-17 padded (conflict-free)
    if (tid < KK * DD) {
        const int k = tid >> 4, d = tid & 15;
        cs[k * 17 + d] = ws[WS_SUMS + (b * KK + k) * DD + d] / ws[WS_CNTS + b * KK + k];
    }
    __syncthreads();

    const float4* dp4 = (const float4*)(data + (size_t)b * DD * NN);
    const int4*   lp4 = (const int4*)(labels + (size_t)b * NN);
    const int g = blk * T + tid;         // one float4-group (4 points) per thread

    int4 lb = lp4[g];
    int labs[4] = {lb.x, lb.y, lb.z, lb.w};
    float ss[4] = {0.f, 0.f, 0.f, 0.f};
#pragma unroll 4
    for (int d = 0; d < DD; ++d) {
        float4 x = dp4[(size_t)d * G4 + g];      // 1 KB contiguous per wave
        float xs[4] = {x.x, x.y, x.z, x.w};
#pragma unroll
        for (int p = 0; p < 4; ++p) {
            float c  = cs[labs[p] * 17 + d];     // broadcast / distinct banks
            float df = xs[p] - c;
            ss[p] = fmaf(df, df, ss[p]);
        }
    }

    float acc[KK];
#pragma unroll
    for (int k = 0; k < KK; ++k) acc[k] = 0.f;
#pragma unroll
    for (int p = 0; p < 4; ++p) {
        float e  = fmaxf(sqrtf(ss[p]) - 1.0f, 0.f);   // DELTA_VAR = 1
        float e2 = e * e;
#pragma unroll
        for (int k = 0; k < KK; ++k) acc[k] += (labs[p] == k) ? e2 : 0.f;
    }

    const int lane = tid & 63, wv = tid >> 6;
#pragma unroll
    for (int k = 0; k < KK; ++k) {
#pragma unroll
        for (int m = 1; m < 64; m <<= 1) acc[k] += __shfl_xor(acc[k], m, 64);
    }
    __shared__ float vred[WV][KK];
    if (lane == 0) {
#pragma unroll
        for (int k = 0; k < KK; ++k) vred[wv][k] = acc[k];
    }
    __syncthreads();
    if (tid < KK) {
        float v = 0.f;
#pragma unroll
        for (int q = 0; q < WV; ++q) v += vred[q][tid];
        atomicAdd(&ws[WS_VARSUMS + b * KK + tid], v);
    }
}

// ---------------- Final: centers + dist/reg/var combine ---------------------
__global__ void k_final(const float* __restrict__ ws, float* __restrict__ out) {
    const int t = threadIdx.x;           // 0..63 : b = t>>3, k = t&7
    const int b = t >> 3, k = t & 7;
    const float inv = 1.0f / ws[WS_CNTS + t];
    __shared__ float sc[BB * KK][DD];
    float cen[DD];
    float n2 = 0.f;
#pragma unroll
    for (int d = 0; d < DD; ++d) {
        float v = ws[WS_SUMS + t * DD + d] * inv;
        cen[d] = v;
        sc[t][d] = v;
        n2 = fmaf(v, v, n2);
    }
    __syncthreads();
    float rg = fmaxf(sqrtf(n2) - 4.0f, 0.f);   // delta_reg = sqrt(16) = 4
    rg *= rg;
    float rowcost = 0.f;
#pragma unroll
    for (int j = 0; j < KK; ++j) {
        float d2 = 0.f;
#pragma unroll
        for (int d = 0; d < DD; ++d) {
            float df = cen[d] - sc[b * KK + j][d];
            d2 = fmaf(df, df, d2);
        }
        float dm = sqrtf(d2) + ((j == k) ? 2.0f : 0.0f);   // eye*DELTA_DIST trick
        float h = fmaxf(2.0f - dm, 0.f);
        rowcost += h * h;
    }
    float var  = ws[WS_VARSUMS + t] * inv;
    float term = var / (float)KK + rowcost / 56.0f + rg / (float)KK;
#pragma unroll
    for (int m = 1; m < 64; m <<= 1) term += __shfl_xor(term, m, 64);
    if (t == 0) out[0] = term / (float)BB;
}

extern "C" void kernel_launch(void* const* d_in, const int* in_sizes, int n_in,
                              void* d_out, int out_size, void* d_ws, size_t ws_size,
                              hipStream_t stream) {
    const float* data   = (const float*)d_in[0];
    const int*   labels = (const int*)d_in[1];
    float*       ws     = (float*)d_ws;

    hipMemsetAsync(d_ws, 0, WS_TOTAL * sizeof(float), stream);
    k_sums<<<BB * BPB, T, 0, stream>>>(data, labels, ws);
    k_var<<<BB * BPB, T, 0, stream>>>(data, labels, ws);
    k_final<<<1, 64, 0, stream>>>(ws, (float*)d_out);
}